// Round 18
// baseline (1720.260 us; speedup 1.0000x reference)
//
#include <hip/hip_runtime.h>

#define TT 2048
#define BB 256
#define FF 64
#define HH 128
#define NT 512            // 8 waves; wave w owns units [16w, 16w+16)
#define MR 8              // batch rows per block: two independent groups of 4
#define NBLK (BB / MR)    // 32 blocks
#define RS (BB * FF / 4)  // x row stride in float4
#define HSTR 320          // LDS row stride (bytes); within-inst 2-way alias only

typedef _Float16 half8 __attribute__((ext_vector_type(8)));
typedef _Float16 half4 __attribute__((ext_vector_type(4)));
typedef float    f32x4 __attribute__((ext_vector_type(4)));

#if __has_builtin(__builtin_amdgcn_rcpf)
#define FRCP(v) __builtin_amdgcn_rcpf(v)
#else
#define FRCP(v) (1.0f / (v))
#endif

// D = A(16x32 f16) * B(32x16 f16) + C(f32). Operand conventions verified in
// rounds 14-16 (absmax 0.0039 each).
__device__ __forceinline__ f32x4 mf(f32x4 a, f32x4 b, f32x4 c) {
  return __builtin_amdgcn_mfma_f32_16x16x32_f16(
      __builtin_bit_cast(half8, a), __builtin_bit_cast(half8, b), c, 0, 0, 0);
}

// Hot-loop barrier without the vmcnt(0) drain (r9: proven equivalent).
__device__ __forceinline__ void step_barrier() {
  asm volatile("s_waitcnt lgkmcnt(0)" ::: "memory");
  __builtin_amdgcn_s_barrier();
  __builtin_amdgcn_sched_barrier(0);
}

__global__ void __launch_bounds__(NT)
__attribute__((amdgpu_waves_per_eu(2, 2)))
gru_scan_kernel(const float* __restrict__ x,     // [T,B,F]
                const float* __restrict__ Wi,    // [F,3H] r|z|n
                const float* __restrict__ bi,    // [3H]
                const float* __restrict__ Whrz,  // [H,2H] r|z
                const float* __restrict__ Whn,   // [H,H]
                const float* __restrict__ bn,    // [H]
                float* __restrict__ out)         // [T,B,H]
{
  const int tid   = threadIdx.x;
  const int w     = tid >> 6;     // wave 0..7
  const int l     = tid & 63;
  const int n16   = l & 15;       // C col within tile / A row m
  const int q     = l >> 4;       // k-chunk group; also this lane's batch row
  const int u     = 16 * w + n16; // hidden unit (this thread's column)
  const int rr    = n16 & 3;      // replicated A row (within each group)
  const int brow0 = blockIdx.x * MR;

  // 8-row staging, f16, row stride 320B. Group A = rows 0-3, B = rows 4-7.
  __shared__ __align__(16) char h_lds[2][MR * HSTR];   // 2 x 2560 B
  __shared__ __align__(16) char x_lds[4][MR * HSTR];   // 4 x 2560 B

  // ---- B-fragments (natural k order, col u) — SHARED by both groups ----
  f32x4 Bhr[4], Bhz[4], Bhn2[4];
  f32x4 Bxr[2], Bxz[2], Bxn2[2];
  #pragma unroll
  for (int kt = 0; kt < 4; ++kt) {
    half8 fr, fz, fn;
    #pragma unroll
    for (int j = 0; j < 8; ++j) {
      const int k = 32 * kt + 8 * q + j;       // 0..127
      fr[j] = (_Float16)Whrz[(size_t)k * 256 + u];
      fz[j] = (_Float16)Whrz[(size_t)k * 256 + 128 + u];
      fn[j] = (_Float16)Whn[(size_t)k * 128 + u];
    }
    Bhr[kt]  = __builtin_bit_cast(f32x4, fr);
    Bhz[kt]  = __builtin_bit_cast(f32x4, fz);
    Bhn2[kt] = __builtin_bit_cast(f32x4, fn);
  }
  #pragma unroll
  for (int kt = 0; kt < 2; ++kt) {
    half8 fr, fz, fn;
    #pragma unroll
    for (int j = 0; j < 8; ++j) {
      const int k = 32 * kt + 8 * q + j;       // 0..63
      fr[j] = (_Float16)Wi[(size_t)k * 384 + u];
      fz[j] = (_Float16)Wi[(size_t)k * 384 + 128 + u];
      fn[j] = (_Float16)Wi[(size_t)k * 384 + 256 + u];
    }
    Bxr[kt]  = __builtin_bit_cast(f32x4, fr);
    Bxz[kt]  = __builtin_bit_cast(f32x4, fz);
    Bxn2[kt] = __builtin_bit_cast(f32x4, fn);
  }
  // biases as scalars, applied in the gate tail (C zero-seeded)
  const float bR = bi[u], bZ = bi[128 + u], bX = bi[256 + u], bH = bn[u];
  const f32x4 Zf = f32x4{0.f, 0.f, 0.f, 0.f};

  // A-fragment byte offsets (group A rows; group B = +4*HSTR immediate)
  int hA[4], xA[2];
  #pragma unroll
  for (int kt = 0; kt < 4; ++kt) hA[kt] = rr * HSTR + kt * 64 + q * 16;
  #pragma unroll
  for (int kt = 0; kt < 2; ++kt) xA[kt] = rr * HSTR + kt * 64 + q * 16;
  const int hWA = q * HSTR + 2 * u;             // h'-write, group A
  const int hWB = (q + 4) * HSTR + 2 * u;       // h'-write, group B

  // x staging: 128 loader threads -> (row 0..7, 4-feature group)
  const bool loader = (tid < 128);
  const int  srow   = tid >> 4;   // 0..7 (loader only)
  const int  sc     = tid & 15;
  const int  sbyte  = srow * HSTR + sc * 8;

  // ---- init: h[0] = 0 (8 rows); stage x[0],x[1]; prefetch x[2],x[3] ----
  if (loader) {
    *(f32x4*)(h_lds[0] + srow * HSTR + sc * 16) = Zf;
    #pragma unroll
    for (int s = 0; s < 2; ++s) {
      const float4 v =
          *(const float4*)(x + ((size_t)s * BB + brow0 + srow) * FF + sc * 4);
      half4 hf;
      hf[0] = (_Float16)v.x; hf[1] = (_Float16)v.y;
      hf[2] = (_Float16)v.z; hf[3] = (_Float16)v.w;
      *(half4*)(x_lds[s] + sbyte) = hf;
    }
  }
  const float4* xsrc =
      (const float4*)(x + ((size_t)2 * BB + brow0 + srow) * FF + sc * 4);
  float4 xva, xvb;
  if (loader) {
    xva = xsrc[0];              // x[2]
    xvb = xsrc[(size_t)RS];     // x[3]
    xsrc += 2 * (size_t)RS;     // -> x[4]
  }

  float h_oldA = 0.0f;          // (row q,   unit u)
  float h_oldB = 0.0f;          // (row q+4, unit u)
  float* outpA = out + ((size_t)brow0 + q) * HH + u;
  float* outpB = outpA + 4 * HH;
  __syncthreads();

  // one lane-local element from the replicated C fragment (row q)
#define SEL(C_) ((q < 2) ? ((q == 0) ? (C_)[0] : (C_)[1])                   \
                         : ((q == 2) ? (C_)[2] : (C_)[3]))
  // fused 5-trans gate (verified r15/r16); hdst_ = next h buffer base
#define GATE(cr_, cz_, chn_, cxn_, hold_, hdst_, hW_, outp_)                \
  {                                                                         \
    const float A_ = __expf(-((cr_) + bR));                                 \
    const float rg = FRCP(1.0f + A_);                                       \
    const float B_ = __expf(-((cz_) + bZ));                                 \
    const float na = ((cxn_) + bX) + rg * ((chn_) + bH);                    \
    const float E_ = __expf(2.0f * na);                                     \
    const float Ep1 = E_ + 1.0f;                                            \
    const float num = (hold_) * Ep1 + B_ * (E_ - 1.0f);                     \
    const float hv  = num * FRCP(Ep1 * (1.0f + B_));                        \
    (hold_) = hv;                                                           \
    *(_Float16*)((hdst_) + (hW_)) = (_Float16)hv;                           \
    *(outp_) = hv;                                                          \
  }

#define GEMM(Ah0, Ah1, Ah2, Ah3, Ax0, Ax1, Cr, Cz, Chn, Cxn)               \
    f32x4 Cr = mf(Ah0, Bhr[0], Zf);                                         \
    Cr = mf(Ah1, Bhr[1], Cr); Cr = mf(Ah2, Bhr[2], Cr);                     \
    Cr = mf(Ah3, Bhr[3], Cr);                                               \
    Cr = mf(Ax0, Bxr[0], Cr); Cr = mf(Ax1, Bxr[1], Cr);                     \
    f32x4 Cz = mf(Ah0, Bhz[0], Zf);                                         \
    Cz = mf(Ah1, Bhz[1], Cz); Cz = mf(Ah2, Bhz[2], Cz);                     \
    Cz = mf(Ah3, Bhz[3], Cz);                                               \
    Cz = mf(Ax0, Bxz[0], Cz); Cz = mf(Ax1, Bxz[1], Cz);                     \
    f32x4 Chn = mf(Ah0, Bhn2[0], Zf);                                       \
    Chn = mf(Ah1, Bhn2[1], Chn); Chn = mf(Ah2, Bhn2[2], Chn);               \
    Chn = mf(Ah3, Bhn2[3], Chn);                                            \
    f32x4 Cxn = mf(Ax0, Bxn2[0], Zf);                                       \
    Cxn = mf(Ax1, Bxn2[1], Cxn);

#define STEP(P, XV)                                                         \
  {                                                                         \
    const int t_ = tbase + (P);                                             \
    const char* hb = h_lds[(P) & 1];                                        \
    const char* xb = x_lds[(P) & 3];                                        \
    char* hdst = h_lds[((P) + 1) & 1];                                      \
    /* group A fragments (rows 0-3) */                                      \
    f32x4 aAh0 = *(const f32x4*)(hb + hA[0]);                               \
    f32x4 aAh1 = *(const f32x4*)(hb + hA[1]);                               \
    f32x4 aAh2 = *(const f32x4*)(hb + hA[2]);                               \
    f32x4 aAh3 = *(const f32x4*)(hb + hA[3]);                               \
    f32x4 aAx0 = *(const f32x4*)(xb + xA[0]);                               \
    f32x4 aAx1 = *(const f32x4*)(xb + xA[1]);                               \
    /* group B fragments (rows 4-7) */                                      \
    f32x4 bAh0 = *(const f32x4*)(hb + 4 * HSTR + hA[0]);                    \
    f32x4 bAh1 = *(const f32x4*)(hb + 4 * HSTR + hA[1]);                    \
    f32x4 bAh2 = *(const f32x4*)(hb + 4 * HSTR + hA[2]);                    \
    f32x4 bAh3 = *(const f32x4*)(hb + 4 * HSTR + hA[3]);                    \
    f32x4 bAx0 = *(const f32x4*)(xb + 4 * HSTR + xA[0]);                    \
    f32x4 bAx1 = *(const f32x4*)(xb + 4 * HSTR + xA[1]);                    \
    if (loader) {                                                           \
      if (t_ + 2 < TT) {                                                    \
        half4 hf;                                                           \
        hf[0] = (_Float16)XV.x; hf[1] = (_Float16)XV.y;                     \
        hf[2] = (_Float16)XV.z; hf[3] = (_Float16)XV.w;                     \
        *(half4*)(x_lds[((P) + 2) & 3] + sbyte) = hf;        /* x[t+2] */   \
      }                                                                     \
      if (t_ + 4 < TT) { XV = *xsrc; xsrc += RS; }           /* x[t+4] */   \
    }                                                                       \
    /* two independent GEMM+gate chains -> scheduler fills bubbles */       \
    GEMM(aAh0, aAh1, aAh2, aAh3, aAx0, aAx1, CrA, CzA, ChnA, CxnA)          \
    GEMM(bAh0, bAh1, bAh2, bAh3, bAx0, bAx1, CrB, CzB, ChnB, CxnB)          \
    GATE(SEL(CrA), SEL(CzA), SEL(ChnA), SEL(CxnA), h_oldA, hdst, hWA, outpA)\
    GATE(SEL(CrB), SEL(CzB), SEL(ChnB), SEL(CxnB), h_oldB, hdst, hWB, outpB)\
    outpA += (size_t)BB * HH;                                               \
    outpB += (size_t)BB * HH;                                               \
    step_barrier();                                                         \
  }

  for (int tbase = 0; tbase < TT; tbase += 4) {
    STEP(0, xva)
    STEP(1, xvb)
    STEP(2, xva)
    STEP(3, xvb)
  }
#undef STEP
#undef GEMM
#undef GATE
#undef SEL
}

extern "C" void kernel_launch(void* const* d_in, const int* in_sizes, int n_in,
                              void* d_out, int out_size, void* d_ws, size_t ws_size,
                              hipStream_t stream) {
  const float* x    = (const float*)d_in[0];
  const float* Wi   = (const float*)d_in[1];
  const float* bi   = (const float*)d_in[2];
  const float* Whrz = (const float*)d_in[3];
  const float* Whn  = (const float*)d_in[4];
  const float* bn   = (const float*)d_in[5];
  float* out = (float*)d_out;

  gru_scan_kernel<<<dim3(NBLK), dim3(NT), 0, stream>>>(
      x, Wi, bi, Whrz, Whn, bn, out);
}